// Round 10
// baseline (1426.722 us; speedup 1.0000x reference)
//
#include <hip/hip_runtime.h>
#include <hip/hip_bf16.h>

// Problem constants
#define BB 8
#define SS 2048
#define EE 2048
#define HH 8
// scan chunking: W*T == SS
#define WCH 32
#define TCH 64

typedef __attribute__((ext_vector_type(4))) float f32x4;
typedef __attribute__((ext_vector_type(8))) short s16x8;
typedef __attribute__((ext_vector_type(4))) unsigned short u16x4;
typedef __attribute__((ext_vector_type(8))) unsigned short u16x8;

__device__ inline unsigned short f2bf(float x) {
  unsigned u = __float_as_uint(x);
  unsigned r = (u + 0x7fffu + ((u >> 16) & 1u)) >> 16;   // RNE
  return (unsigned short)r;
}

__device__ inline void gl_lds16(const void* g, void* l) {
  // async global->LDS, 16B per lane; LDS dest must be wave-uniform base + lane*16
  __builtin_amdgcn_global_load_lds(
      (__attribute__((address_space(1))) void*)(void*)(size_t)(const char*)g,
      (__attribute__((address_space(3))) void*)l, 16, 0, 0);
}

// ---------------------------------------------------------------------------
// Kernel: elementwise f32 -> bf16 cast of BOTH weight matrices in one launch
// ---------------------------------------------------------------------------
__global__ __launch_bounds__(256) void cast2_bf16(const float* __restrict__ in1,
                                                  unsigned short* __restrict__ out1,
                                                  const float* __restrict__ in2,
                                                  unsigned short* __restrict__ out2,
                                                  long n_each) {
  long i = ((long)blockIdx.x * 256 + threadIdx.x) * 8;
  const float* in;
  unsigned short* out;
  if (i < n_each) {
    in = in1 + i; out = out1 + i;
  } else {
    in = in2 + (i - n_each); out = out2 + (i - n_each);
  }
  f32x4 a = *(const f32x4*)in;
  f32x4 b = *(const f32x4*)(in + 4);
  u16x8 r;
#pragma unroll
  for (int j = 0; j < 4; ++j) { r[j] = f2bf(a[j]); r[4 + j] = f2bf(b[j]); }
  *(u16x8*)out = r;
}

// ---------------------------------------------------------------------------
// Kernel 1: LN1 + new_m (per (b,s) row). Writes M matrices [bh][s][16][16] f32
// ---------------------------------------------------------------------------
__global__ __launch_bounds__(256) void ln1_newm(const float* __restrict__ acts,
                                                const float* __restrict__ lnw,
                                                const float* __restrict__ wup,
                                                float* __restrict__ Ms) {
  const int row = blockIdx.x;          // b*SS + s
  const int b = row >> 11, s = row & 2047;
  __shared__ float xr[2048];
  __shared__ float wu[272];            // [16][17] padded
  __shared__ float redA[4], redB[4];
  const int t = threadIdx.x, lane = t & 63, w = t >> 6;
  const float* xp = acts + (long)row * EE;
  f32x4 v0 = *(const f32x4*)(xp + t * 4);
  f32x4 v1 = *(const f32x4*)(xp + 1024 + t * 4);
  float sum = 0.f, ss = 0.f;
#pragma unroll
  for (int i = 0; i < 4; ++i) {
    sum += v0[i] + v1[i];
    ss += v0[i] * v0[i] + v1[i] * v1[i];
  }
#pragma unroll
  for (int off = 32; off > 0; off >>= 1) {
    sum += __shfl_down(sum, off, 64);
    ss += __shfl_down(ss, off, 64);
  }
  if (lane == 0) { redA[w] = sum; redB[w] = ss; }
  __syncthreads();
  const float stot = redA[0] + redA[1] + redA[2] + redA[3];
  const float sstot = redB[0] + redB[1] + redB[2] + redB[3];
  const float mu = stot * (1.f / 2048.f);
  const float var = sstot * (1.f / 2048.f) - mu * mu;
  const float rs = rsqrtf(var + 1e-5f);
  f32x4 g0 = *(const f32x4*)(lnw + t * 4);
  f32x4 g1 = *(const f32x4*)(lnw + 1024 + t * 4);
#pragma unroll
  for (int i = 0; i < 4; ++i) {
    xr[t * 4 + i] = (v0[i] - mu) * rs * g0[i];
    xr[1024 + t * 4 + i] = (v1[i] - mu) * rs * g1[i];
  }
  wu[(t >> 4) * 17 + (t & 15)] = wup[t];  // wu[p][c]
  __syncthreads();
  // new_m[o][p] = I[o][p] + sum_c xln[h][o][c] * wup[p][c]
  const int h = t >> 5, idx = t & 31, o = idx >> 1, p0 = (idx & 1) * 8;
  float acc[8] = {0.f, 0.f, 0.f, 0.f, 0.f, 0.f, 0.f, 0.f};
  const int xb = h * 256 + o * 16;
#pragma unroll
  for (int c = 0; c < 16; ++c) {
    const float xa = xr[xb + c];
#pragma unroll
    for (int pp = 0; pp < 8; ++pp) acc[pp] += xa * wu[(p0 + pp) * 17 + c];
  }
  float* mp = Ms + (((long)(b * HH + h)) * SS + s) * 256 + o * 16;
#pragma unroll
  for (int pp = 0; pp < 8; ++pp) {
    const int p = p0 + pp;
    mp[p] = acc[pp] + ((p == o) ? 1.f : 0.f);
  }
}

// ---------------------------------------------------------------------------
// Kernel 2: per-chunk products Q_c = M_{cW} @ ... @ M_{cW+W-1}
// ---------------------------------------------------------------------------
__global__ __launch_bounds__(64) void chunk_prod(const float* __restrict__ Ms,
                                                 float* __restrict__ Qb) {
  const int task = blockIdx.x;             // bh*TCH + ch
  const int bh = task >> 6, ch = task & 63;
  const float* Mbase = Ms + ((long)bh * SS + ch * WCH) * 256;
  __shared__ float Al[272], Ml[272];
  const int t = threadIdx.x, o = t >> 2, c4 = t & 3;
  f32x4 v = *(const f32x4*)(Mbase + t * 4);
#pragma unroll
  for (int i = 0; i < 4; ++i) Al[o * 17 + c4 * 4 + i] = v[i];
  for (int j = 1; j < WCH; ++j) {
    f32x4 mv = *(const f32x4*)(Mbase + (long)j * 256 + t * 4);
    __syncthreads();
#pragma unroll
    for (int i = 0; i < 4; ++i) Ml[o * 17 + c4 * 4 + i] = mv[i];
    __syncthreads();
    float nr[4] = {0.f, 0.f, 0.f, 0.f};
#pragma unroll
    for (int cc = 0; cc < 16; ++cc) {
      const float a = Al[o * 17 + cc];
#pragma unroll
      for (int i = 0; i < 4; ++i) nr[i] += a * Ml[cc * 17 + c4 * 4 + i];
    }
    __syncthreads();
#pragma unroll
    for (int i = 0; i < 4; ++i) Al[o * 17 + c4 * 4 + i] = nr[i];
  }
  f32x4 q;
#pragma unroll
  for (int i = 0; i < 4; ++i) q[i] = Al[o * 17 + c4 * 4 + i];
  *(f32x4*)(Qb + (long)task * 256 + t * 4) = q;
}

// ---------------------------------------------------------------------------
// Kernel 3: sequential scan of chunk products
// ---------------------------------------------------------------------------
__global__ __launch_bounds__(64) void chunk_scan(const float* __restrict__ last,
                                                 const float* __restrict__ Qb,
                                                 float* __restrict__ Rb) {
  const int bh = blockIdx.x;
  const int t = threadIdx.x, o = t >> 2, c4 = t & 3;
  __shared__ float Al[272], Ml[272];
  f32x4 v = *(const f32x4*)(last + (long)bh * 256 + t * 4);
#pragma unroll
  for (int i = 0; i < 4; ++i) Al[o * 17 + c4 * 4 + i] = v[i];
  *(f32x4*)(Rb + (long)bh * TCH * 256 + t * 4) = v;   // R_0
  for (int c = 0; c < TCH - 1; ++c) {
    f32x4 q = *(const f32x4*)(Qb + ((long)bh * TCH + c) * 256 + t * 4);
    __syncthreads();
#pragma unroll
    for (int i = 0; i < 4; ++i) Ml[o * 17 + c4 * 4 + i] = q[i];
    __syncthreads();
    float nr[4] = {0.f, 0.f, 0.f, 0.f};
#pragma unroll
    for (int cc = 0; cc < 16; ++cc) {
      const float a = Al[o * 17 + cc];
#pragma unroll
      for (int i = 0; i < 4; ++i) nr[i] += a * Ml[cc * 17 + c4 * 4 + i];
    }
    __syncthreads();
#pragma unroll
    for (int i = 0; i < 4; ++i) Al[o * 17 + c4 * 4 + i] = nr[i];
    f32x4 w;
#pragma unroll
    for (int i = 0; i < 4; ++i) w[i] = nr[i];
    *(f32x4*)(Rb + ((long)bh * TCH + c + 1) * 256 + t * 4) = w;
  }
}

// ---------------------------------------------------------------------------
// Kernel 4: apply prefixes + fused mru_out/residual + new_state
// ---------------------------------------------------------------------------
__global__ __launch_bounds__(64) void scan_apply(const float* __restrict__ Ms,
                                                 const float* __restrict__ Rb,
                                                 const float* __restrict__ acts,
                                                 const float* __restrict__ wdown,
                                                 float* __restrict__ out) {
  const int task = blockIdx.x;
  const int bh = task >> 6, ch = task & 63;
  const int b = bh >> 3, h = bh & 7;
  const int t = threadIdx.x, o = t >> 2, c4 = t & 3;
  __shared__ float Al[272], Ml[272], Wd[272];
  f32x4 r0 = *(const f32x4*)(Rb + (long)task * 256 + t * 4);
#pragma unroll
  for (int i = 0; i < 4; ++i) Al[o * 17 + c4 * 4 + i] = r0[i];
  f32x4 wv = *(const f32x4*)(wdown + t * 4);   // wdown[c'][p], flat
#pragma unroll
  for (int i = 0; i < 4; ++i) Wd[o * 17 + c4 * 4 + i] = wv[i];
  for (int j = 0; j < WCH; ++j) {
    const int s = ch * WCH + j;
    f32x4 mv = *(const f32x4*)(Ms + ((long)bh * SS + s) * 256 + t * 4);
    __syncthreads();
#pragma unroll
    for (int i = 0; i < 4; ++i) Ml[o * 17 + c4 * 4 + i] = mv[i];
    __syncthreads();
    float nr[4] = {0.f, 0.f, 0.f, 0.f};
#pragma unroll
    for (int cc = 0; cc < 16; ++cc) {
      const float a = Al[o * 17 + cc];
#pragma unroll
      for (int i = 0; i < 4; ++i) nr[i] += a * Ml[cc * 17 + c4 * 4 + i];
    }
    __syncthreads();
#pragma unroll
    for (int i = 0; i < 4; ++i) Al[o * 17 + c4 * 4 + i] = nr[i];
    __syncthreads();
    float o2[4] = {0.f, 0.f, 0.f, 0.f};
#pragma unroll
    for (int p = 0; p < 16; ++p) {
      const float pr = Al[o * 17 + p];
#pragma unroll
      for (int i = 0; i < 4; ++i) o2[i] += pr * Wd[(c4 * 4 + i) * 17 + p];
    }
    const long e = ((long)(b * SS + s)) * EE + h * 256 + t * 4;
    f32x4 av = *(const f32x4*)(acts + e);
    f32x4 res;
#pragma unroll
    for (int i = 0; i < 4; ++i) res[i] = av[i] + o2[i];
    *(f32x4*)(out + e) = res;
    if (b == BB - 1) {
      f32x4 st;
#pragma unroll
      for (int i = 0; i < 4; ++i) st[i] = nr[i];
      *(f32x4*)(out + (long)BB * SS * EE + ((long)s * HH + h) * 256 + t * 4) = st;
    }
  }
}

// ---------------------------------------------------------------------------
// Kernel 5: LN2 + bf16 cast
// ---------------------------------------------------------------------------
__global__ __launch_bounds__(256) void ln2_cast(const float* __restrict__ act1,
                                                const float* __restrict__ lnw,
                                                unsigned short* __restrict__ xbf) {
  const int row = blockIdx.x;
  __shared__ float redA[4], redB[4];
  const int t = threadIdx.x, lane = t & 63, w = t >> 6;
  const float* xp = act1 + (long)row * EE;
  f32x4 v0 = *(const f32x4*)(xp + t * 4);
  f32x4 v1 = *(const f32x4*)(xp + 1024 + t * 4);
  float sum = 0.f, ss = 0.f;
#pragma unroll
  for (int i = 0; i < 4; ++i) {
    sum += v0[i] + v1[i];
    ss += v0[i] * v0[i] + v1[i] * v1[i];
  }
#pragma unroll
  for (int off = 32; off > 0; off >>= 1) {
    sum += __shfl_down(sum, off, 64);
    ss += __shfl_down(ss, off, 64);
  }
  if (lane == 0) { redA[w] = sum; redB[w] = ss; }
  __syncthreads();
  const float stot = redA[0] + redA[1] + redA[2] + redA[3];
  const float sstot = redB[0] + redB[1] + redB[2] + redB[3];
  const float mu = stot * (1.f / 2048.f);
  const float var = sstot * (1.f / 2048.f) - mu * mu;
  const float rs = rsqrtf(var + 1e-5f);
  f32x4 g0 = *(const f32x4*)(lnw + t * 4);
  f32x4 g1 = *(const f32x4*)(lnw + 1024 + t * 4);
  u16x4 o0, o1;
#pragma unroll
  for (int i = 0; i < 4; ++i) {
    o0[i] = f2bf((v0[i] - mu) * rs * g0[i]);
    o1[i] = f2bf((v1[i] - mu) * rs * g1[i]);
  }
  *(u16x4*)(xbf + (long)row * EE + t * 4) = o0;
  *(u16x4*)(xbf + (long)row * EE + 1024 + t * 4) = o1;
}

// ---------------------------------------------------------------------------
// GEMM 256x256, BK=64, 8 waves. Depth-3 8-phase schedule (template-faithful
// vmcnt(6) = 3 half-tiles in flight). MFMA quadrant order per tile:
// ph1 Q(0,0) [A0xB0], ph2 Q(4,0) [A1xB0 held], ph3 Q(4,2) [A1 held x B1],
// ph4 Q(0,2) [A0 re-read x B1 held] — frees each unit 1 phase after its last
// ds_read, enabling stage order:
//   ph1: Ao0(t+1), ph2: Be0(t+2), ph3: Ae1(t+2), ph4: Be1(t+2),
//   ph5: Ae0(t+2), ph6: Bo0(t+3), ph7: Ao1(t+3), ph8: Bo1(t+3)
// Every unit staged 4-11 phases before first read. vmcnt(6) at ph4/ph8 only
// needs the 3-phase-old stage landed. Tail: ph4 vmcnt(0) when !s2; ph8
// vmcnt(6)/vmcnt(0)/skip for s3/s2-only/last. Lifetimes audited.
// EPI=0: gelu->bf16; EPI=1: f32 +=.
// ---------------------------------------------------------------------------
#define MFMA16 __builtin_amdgcn_mfma_f32_16x16x32_bf16
#define SBAR() __builtin_amdgcn_s_barrier()
#define SPRIO(x) __builtin_amdgcn_s_setprio(x)

template <int EPI>
__global__ __launch_bounds__(512, 2) void gemm8p(const short* __restrict__ A,
                                                 const short* __restrict__ Bt,
                                                 void* __restrict__ C,
                                                 int M, int N, int K) {
  __shared__ short lds[65536];  // 128 KiB = 8 x 16KB half-units
  const int tid = threadIdx.x;
  const int lane = tid & 63;
  const int wid = tid >> 6;
  const int wm = wid >> 2, wn = wid & 3;
  const int r = lane & 15, kq = lane >> 4;

  // bijective XCD swizzle (nwg % 8 == 0 for both GEMMs)
  const int nx = gridDim.x;
  const int orig = blockIdx.y * nx + blockIdx.x;
  const int nwg = nx * gridDim.y;
  const int swz = (orig & 7) * (nwg >> 3) + (orig >> 3);
  const int by = swz / nx, bx = swz - by * nx;
  const long m0 = (long)by * 256, n0 = (long)bx * 256;

  const int NT = K >> 6;   // K-tiles (NT even: K multiple of 128)

  f32x4 acc[8][4];
#pragma unroll
  for (int i = 0; i < 8; ++i)
#pragma unroll
    for (int j = 0; j < 4; ++j) acc[i][j] = (f32x4){0.f, 0.f, 0.f, 0.f};

  // stage addressing: one half-unit = 128 rows x 64 cols bf16 = 16KB = 2 loads/thread
  // rule-21: linear LDS dest, pre-swizzled global source (chunk ^ row&7)
  long sA0[2], sB0[2];
  int dst[2];
#pragma unroll
  for (int j = 0; j < 2; ++j) {
    const int c = tid + 512 * j;
    const int row = c >> 3;             // 0..127 within half-unit
    const int kc = (c & 7) ^ (row & 7);
    sA0[j] = (m0 + row) * (long)K + kc * 8;
    sB0[j] = (n0 + row) * (long)K + kc * 8;
    dst[j] = c * 8;                     // shorts within unit
  }
  const long hK = 128 * (long)K;

#define STG_A(t2, h) { const int _u = (((t2) & 1) * 2 + (h)) * 8192; \
  const long _o = (long)((t2) << 6) + (h) * hK; \
  _Pragma("unroll") for (int _j = 0; _j < 2; ++_j) \
    gl_lds16(A + sA0[_j] + _o, &lds[_u + dst[_j]]); }
#define STG_B(t2, h) { const int _u = 32768 + (((t2) & 1) * 2 + (h)) * 8192; \
  const long _o = (long)((t2) << 6) + (h) * hK; \
  _Pragma("unroll") for (int _j = 0; _j < 2; ++_j) \
    gl_lds16(Bt + sB0[_j] + _o, &lds[_u + dst[_j]]); }

  // ds_read offsets (shorts); swizzle bit depends only on r&7
  int offA[4], offB[2];
#pragma unroll
  for (int i = 0; i < 4; ++i) offA[i] = (wm * 64 + i * 16 + r) * 64;
#pragma unroll
  for (int j = 0; j < 2; ++j) offB[j] = (wn * 32 + j * 16 + r) * 64;
  const int c0 = (kq ^ (r & 7)) * 8;
  const int c1 = ((4 + kq) ^ (r & 7)) * 8;

  s16x8 af[4][2], bf[2][2];

#define RD_A(h, pb) { _Pragma("unroll") for (int _i = 0; _i < 4; ++_i) { \
    const int _ba = ((pb) + (h)) * 8192 + offA[_i]; \
    af[_i][0] = *(const s16x8*)&lds[_ba + c0]; \
    af[_i][1] = *(const s16x8*)&lds[_ba + c1]; } }
#define RD_B(h, pb) { _Pragma("unroll") for (int _j = 0; _j < 2; ++_j) { \
    const int _bb = 32768 + ((pb) + (h)) * 8192 + offB[_j]; \
    bf[_j][0] = *(const s16x8*)&lds[_bb + c0]; \
    bf[_j][1] = *(const s16x8*)&lds[_bb + c1]; } }
#define MFMA_Q(I0, J0) { _Pragma("unroll") for (int _i = 0; _i < 4; ++_i) \
  _Pragma("unroll") for (int _j = 0; _j < 2; ++_j) { \
    acc[(I0) + _i][(J0) + _j] = MFMA16(af[_i][0], bf[_j][0], acc[(I0) + _i][(J0) + _j], 0, 0, 0); \
    acc[(I0) + _i][(J0) + _j] = MFMA16(af[_i][1], bf[_j][1], acc[(I0) + _i][(J0) + _j], 0, 0, 0); } }

  // prologue: tile0 (4 units) + Bo0,Ao1,Bo1 of tile1 = 7 half-tiles;
  // vmcnt(6) -> tile0's 4 landed, newest 3 (t1 units) stay in flight.
  STG_A(0, 0); STG_A(0, 1); STG_B(0, 0); STG_B(0, 1);
  STG_B(1, 0); STG_A(1, 1); STG_B(1, 1);
  asm volatile("s_waitcnt vmcnt(6)" ::: "memory");
  SBAR();

  for (int t = 0; t < NT; t += 2) {
    const bool s2 = (t + 2) < NT, s3 = (t + 3) < NT;
    // ===== tile t (even, par 0) =====
    // ph1: A0xB0 -> acc[0..3][0..1]; stage Ao0(t+1)
    RD_A(0, 0); RD_B(0, 0);
    STG_A(t + 1, 0);
    asm volatile("s_waitcnt lgkmcnt(8)" ::: "memory");
    SBAR();
    SPRIO(1); MFMA_Q(0, 0); SPRIO(0);
    SBAR();
    // ph2: A1xB0(held) -> acc[4..7][0..1]; stage Be0(t+2)
    RD_A(1, 0);
    if (s2) STG_B(t + 2, 0);
    SBAR();
    SPRIO(1); MFMA_Q(4, 0); SPRIO(0);
    SBAR();
    // ph3: A1(held)xB1 -> acc[4..7][2..3]; stage Ae1(t+2)
    RD_B(1, 0);
    if (s2) STG_A(t + 2, 1);
    SBAR();
    SPRIO(1); MFMA_Q(4, 2); SPRIO(0);
    SBAR();
    // ph4: A0(re-read)xB1(held) -> acc[0..3][2..3]; stage Be1(t+2); wait
    RD_A(0, 0);
    if (s2) STG_B(t + 2, 1);
    SBAR();
    SPRIO(1); MFMA_Q(0, 2); SPRIO(0);
    if (s2) { asm volatile("s_waitcnt vmcnt(6)" ::: "memory"); }
    else    { asm volatile("s_waitcnt vmcnt(0)" ::: "memory"); }
    SBAR();
    // ===== tile t+1 (odd, par 1) =====
    // ph5: A0xB0; stage Ae0(t+2)
    RD_A(0, 2); RD_B(0, 2);
    if (s2) STG_A(t + 2, 0);
    asm volatile("s_waitcnt lgkmcnt(8)" ::: "memory");
    SBAR();
    SPRIO(1); MFMA_Q(0, 0); SPRIO(0);
    SBAR();
    // ph6: A1xB0(held); stage Bo0(t+3)
    RD_A(1, 2);
    if (s3) STG_B(t + 3, 0);
    SBAR();
    SPRIO(1); MFMA_Q(4, 0); SPRIO(0);
    SBAR();
    // ph7: A1(held)xB1; stage Ao1(t+3)
    RD_B(1, 2);
    if (s3) STG_A(t + 3, 1);
    SBAR();
    SPRIO(1); MFMA_Q(4, 2); SPRIO(0);
    SBAR();
    // ph8: A0(re-read)xB1(held); stage Bo1(t+3); wait
    RD_A(0, 2);
    if (s3) STG_B(t + 3, 1);
    SBAR();
    SPRIO(1); MFMA_Q(0, 2); SPRIO(0);
    if (s3)      { asm volatile("s_waitcnt vmcnt(6)" ::: "memory"); }
    else if (s2) { asm volatile("s_waitcnt vmcnt(0)" ::: "memory"); }
    SBAR();
  }
  // after last ph8 SBAR all LDS reads are drained -> lds reusable by epilogue

  // ---------------- LDS-staged coalesced epilogue ----------------
  // Per-wave private region, no cross-wave sync needed.
  // Frag (i,j,rr): in-wave row rs = (i>>2)*64 + (i&3)*16 + kq*4 + rr (0..127)
  //                strip s = j>>1, in-strip col cs = (j&1)*16 + r (0..31)
  // global row = m0 + wm*64 + (rs&63) + (rs>>6)*128
  // global col = n0 + s*128 + wn*32 + cs
  if (EPI == 0) {
    // bf16 out, gelu. Region: 8192 shorts/wave; strip s at +s*4096, [128][32].
    unsigned short* Wl = (unsigned short*)lds + wid * 8192;
#pragma unroll
    for (int i = 0; i < 8; ++i)
#pragma unroll
      for (int j = 0; j < 4; ++j)
#pragma unroll
        for (int rr = 0; rr < 4; ++rr) {
          const int rs = (i >> 2) * 64 + (i & 3) * 16 + kq * 4 + rr;
          const int cs = (j & 1) * 16 + r;
          const float v = acc[i][j][rr];
          const float g = 0.5f * v * (1.0f + erff(v * 0.70710678118654752f));
          Wl[(j >> 1) * 4096 + rs * 32 + cs] = f2bf(g);
        }
    unsigned short* Cb = (unsigned short*)C;
#pragma unroll
    for (int s = 0; s < 2; ++s) {
      const long cg = n0 + s * 128 + wn * 32 + (lane & 3) * 8;
#pragma unroll
      for (int it = 0; it < 8; ++it) {
        const int rs = it * 16 + (lane >> 2);
        u16x8 v = *(const u16x8*)&Wl[s * 4096 + rs * 32 + (lane & 3) * 8];
        const long rg = m0 + wm * 64 + (rs & 63) + (rs >> 6) * 128;
        *(u16x8*)&Cb[rg * N + cg] = v;   // 16B coalesced store
      }
    }
  } else {
    // f32 +=. Region: 4096 floats/wave, one strip [128][32] at a time.
    float* Wl = (float*)lds + wid * 4096;
    float* Cf = (float*)C;
#pragma unroll
    for (int s = 0; s < 2; ++s) {
#pragma unroll
      for (int i = 0; i < 8; ++i)
#pragma unroll
        for (int j = 0; j < 2; ++j)
#pragma unroll
          for (int rr = 0; rr < 4; ++rr) {
            const int rs = (i >> 2) * 64 + (i & 3) * 16 + kq * 4 + rr;
            const int cs = j * 16 + r;
            Wl[rs * 32 + cs] = acc[i][s * 2 + j][rr];
          }
      const long cg = n0 + s * 128 + wn * 32 + (lane & 7) * 4;
#pragma unroll
      for (int it = 0; it < 16; ++it) {
        const int rs = it * 8 + (lane >> 3);
        f32x4 v = *(const f32x4*)&Wl[rs * 32 + (lane & 7) * 4];
        const long rg = m0 + wm * 64 + (rs & 63) + (rs >> 6) * 128;
        float* p = &Cf[rg * N + cg];
        f32x4 o = *(const f32x4*)p;     // 16B coalesced load
#pragma unroll
        for (int e = 0; e < 4; ++e) o[e] += v[e];
        *(f32x4*)p = o;                 // 16B coalesced store
      }
    }
  }
#undef STG_A
#undef STG_B
#undef RD_A
#undef RD_B
#undef MFMA_Q
}

// ---------------------------------------------------------------------------
extern "C" void kernel_launch(void* const* d_in, const int* in_sizes, int n_in,
                              void* d_out, int out_size, void* d_ws, size_t ws_size,
                              hipStream_t stream) {
  const float* acts = (const float*)d_in[0];   // (B,S,E)
  const float* last = (const float*)d_in[1];   // (B,H,O,O)
  const float* ln1w = (const float*)d_in[2];   // (E)
  const float* ln2w = (const float*)d_in[3];   // (E)
  const float* wup = (const float*)d_in[4];    // (O,C)
  const float* wdn = (const float*)d_in[5];    // (C,O)
  const float* w1 = (const float*)d_in[6];     // (4E,E)
  const float* w2 = (const float*)d_in[7];     // (E,4E)
  float* out = (float*)d_out;

  char* ws = (char*)d_ws;
  // ws layout: [xbf 64MB][w1b 32MB][w2b 32MB][X: Ms(128MB)+Q(4MB)+R(4MB) | h1(256MB)]
  unsigned short* xbf = (unsigned short*)ws;                     // 16384*2048 bf16
  unsigned short* w1b = (unsigned short*)(ws + 67108864);        // 8192*2048 bf16
  unsigned short* w2b = (unsigned short*)(ws + 67108864 + 33554432);
  char* X = ws + 134217728;
  float* Ms = (float*)X;                                         // [64][2048][256] f32
  float* Qb = (float*)(X + 134217728);
  float* Rb = (float*)(X + 134217728 + 4194304);
  unsigned short* h1 = (unsigned short*)X;                       // overlays Ms/Q/R

  cast2_bf16<<<16384, 256, 0, stream>>>(w1, w1b, w2, w2b, (long)8192 * 2048);
  ln1_newm<<<BB * SS, 256, 0, stream>>>(acts, ln1w, wup, Ms);
  chunk_prod<<<BB * HH * TCH, 64, 0, stream>>>(Ms, Qb);
  chunk_scan<<<BB * HH, 64, 0, stream>>>(last, Qb, Rb);
  scan_apply<<<BB * HH * TCH, 64, 0, stream>>>(Ms, Rb, acts, wdn, out);
  ln2_cast<<<BB * SS, 256, 0, stream>>>(out, ln2w, xbf);
  dim3 g1(8192 / 256, 16384 / 256);
  gemm8p<0><<<g1, 512, 0, stream>>>((const short*)xbf, (const short*)w1b,
                                    (void*)h1, 16384, 8192, 2048);
  dim3 g2(2048 / 256, 16384 / 256);
  gemm8p<1><<<g2, 512, 0, stream>>>((const short*)h1, (const short*)w2b,
                                    (void*)out, 16384, 2048, 8192);
}

// Round 11
// 1397.959 us; speedup vs baseline: 1.0206x; 1.0206x over previous
//
#include <hip/hip_runtime.h>
#include <hip/hip_bf16.h>

// Problem constants
#define BB 8
#define SS 2048
#define EE 2048
#define HH 8
// scan chunking: W*T == SS
#define WCH 32
#define TCH 64

typedef __attribute__((ext_vector_type(4))) float f32x4;
typedef __attribute__((ext_vector_type(8))) short s16x8;
typedef __attribute__((ext_vector_type(4))) unsigned short u16x4;
typedef __attribute__((ext_vector_type(8))) unsigned short u16x8;

__device__ inline unsigned short f2bf(float x) {
  unsigned u = __float_as_uint(x);
  unsigned r = (u + 0x7fffu + ((u >> 16) & 1u)) >> 16;   // RNE
  return (unsigned short)r;
}

__device__ inline void gl_lds16(const void* g, void* l) {
  // async global->LDS, 16B per lane; LDS dest must be wave-uniform base + lane*16
  __builtin_amdgcn_global_load_lds(
      (__attribute__((address_space(1))) void*)(void*)(size_t)(const char*)g,
      (__attribute__((address_space(3))) void*)l, 16, 0, 0);
}

// ---------------------------------------------------------------------------
// Kernel: elementwise f32 -> bf16 cast of BOTH weight matrices in one launch
// ---------------------------------------------------------------------------
__global__ __launch_bounds__(256) void cast2_bf16(const float* __restrict__ in1,
                                                  unsigned short* __restrict__ out1,
                                                  const float* __restrict__ in2,
                                                  unsigned short* __restrict__ out2,
                                                  long n_each) {
  long i = ((long)blockIdx.x * 256 + threadIdx.x) * 8;
  const float* in;
  unsigned short* out;
  if (i < n_each) {
    in = in1 + i; out = out1 + i;
  } else {
    in = in2 + (i - n_each); out = out2 + (i - n_each);
  }
  f32x4 a = *(const f32x4*)in;
  f32x4 b = *(const f32x4*)(in + 4);
  u16x8 r;
#pragma unroll
  for (int j = 0; j < 4; ++j) { r[j] = f2bf(a[j]); r[4 + j] = f2bf(b[j]); }
  *(u16x8*)out = r;
}

// ---------------------------------------------------------------------------
// Kernel 1: LN1 + new_m (per (b,s) row). Writes M matrices [bh][s][16][16] f32
// ---------------------------------------------------------------------------
__global__ __launch_bounds__(256) void ln1_newm(const float* __restrict__ acts,
                                                const float* __restrict__ lnw,
                                                const float* __restrict__ wup,
                                                float* __restrict__ Ms) {
  const int row = blockIdx.x;          // b*SS + s
  const int b = row >> 11, s = row & 2047;
  __shared__ float xr[2048];
  __shared__ float wu[272];            // [16][17] padded
  __shared__ float redA[4], redB[4];
  const int t = threadIdx.x, lane = t & 63, w = t >> 6;
  const float* xp = acts + (long)row * EE;
  f32x4 v0 = *(const f32x4*)(xp + t * 4);
  f32x4 v1 = *(const f32x4*)(xp + 1024 + t * 4);
  float sum = 0.f, ss = 0.f;
#pragma unroll
  for (int i = 0; i < 4; ++i) {
    sum += v0[i] + v1[i];
    ss += v0[i] * v0[i] + v1[i] * v1[i];
  }
#pragma unroll
  for (int off = 32; off > 0; off >>= 1) {
    sum += __shfl_down(sum, off, 64);
    ss += __shfl_down(ss, off, 64);
  }
  if (lane == 0) { redA[w] = sum; redB[w] = ss; }
  __syncthreads();
  const float stot = redA[0] + redA[1] + redA[2] + redA[3];
  const float sstot = redB[0] + redB[1] + redB[2] + redB[3];
  const float mu = stot * (1.f / 2048.f);
  const float var = sstot * (1.f / 2048.f) - mu * mu;
  const float rs = rsqrtf(var + 1e-5f);
  f32x4 g0 = *(const f32x4*)(lnw + t * 4);
  f32x4 g1 = *(const f32x4*)(lnw + 1024 + t * 4);
#pragma unroll
  for (int i = 0; i < 4; ++i) {
    xr[t * 4 + i] = (v0[i] - mu) * rs * g0[i];
    xr[1024 + t * 4 + i] = (v1[i] - mu) * rs * g1[i];
  }
  wu[(t >> 4) * 17 + (t & 15)] = wup[t];  // wu[p][c]
  __syncthreads();
  // new_m[o][p] = I[o][p] + sum_c xln[h][o][c] * wup[p][c]
  const int h = t >> 5, idx = t & 31, o = idx >> 1, p0 = (idx & 1) * 8;
  float acc[8] = {0.f, 0.f, 0.f, 0.f, 0.f, 0.f, 0.f, 0.f};
  const int xb = h * 256 + o * 16;
#pragma unroll
  for (int c = 0; c < 16; ++c) {
    const float xa = xr[xb + c];
#pragma unroll
    for (int pp = 0; pp < 8; ++pp) acc[pp] += xa * wu[(p0 + pp) * 17 + c];
  }
  float* mp = Ms + (((long)(b * HH + h)) * SS + s) * 256 + o * 16;
#pragma unroll
  for (int pp = 0; pp < 8; ++pp) {
    const int p = p0 + pp;
    mp[p] = acc[pp] + ((p == o) ? 1.f : 0.f);
  }
}

// ---------------------------------------------------------------------------
// Kernel 2: per-chunk products Q_c = M_{cW} @ ... @ M_{cW+W-1}
// ---------------------------------------------------------------------------
__global__ __launch_bounds__(64) void chunk_prod(const float* __restrict__ Ms,
                                                 float* __restrict__ Qb) {
  const int task = blockIdx.x;             // bh*TCH + ch
  const int bh = task >> 6, ch = task & 63;
  const float* Mbase = Ms + ((long)bh * SS + ch * WCH) * 256;
  __shared__ float Al[272], Ml[272];
  const int t = threadIdx.x, o = t >> 2, c4 = t & 3;
  f32x4 v = *(const f32x4*)(Mbase + t * 4);
#pragma unroll
  for (int i = 0; i < 4; ++i) Al[o * 17 + c4 * 4 + i] = v[i];
  for (int j = 1; j < WCH; ++j) {
    f32x4 mv = *(const f32x4*)(Mbase + (long)j * 256 + t * 4);
    __syncthreads();
#pragma unroll
    for (int i = 0; i < 4; ++i) Ml[o * 17 + c4 * 4 + i] = mv[i];
    __syncthreads();
    float nr[4] = {0.f, 0.f, 0.f, 0.f};
#pragma unroll
    for (int cc = 0; cc < 16; ++cc) {
      const float a = Al[o * 17 + cc];
#pragma unroll
      for (int i = 0; i < 4; ++i) nr[i] += a * Ml[cc * 17 + c4 * 4 + i];
    }
    __syncthreads();
#pragma unroll
    for (int i = 0; i < 4; ++i) Al[o * 17 + c4 * 4 + i] = nr[i];
  }
  f32x4 q;
#pragma unroll
  for (int i = 0; i < 4; ++i) q[i] = Al[o * 17 + c4 * 4 + i];
  *(f32x4*)(Qb + (long)task * 256 + t * 4) = q;
}

// ---------------------------------------------------------------------------
// Kernel 3: sequential scan of chunk products
// ---------------------------------------------------------------------------
__global__ __launch_bounds__(64) void chunk_scan(const float* __restrict__ last,
                                                 const float* __restrict__ Qb,
                                                 float* __restrict__ Rb) {
  const int bh = blockIdx.x;
  const int t = threadIdx.x, o = t >> 2, c4 = t & 3;
  __shared__ float Al[272], Ml[272];
  f32x4 v = *(const f32x4*)(last + (long)bh * 256 + t * 4);
#pragma unroll
  for (int i = 0; i < 4; ++i) Al[o * 17 + c4 * 4 + i] = v[i];
  *(f32x4*)(Rb + (long)bh * TCH * 256 + t * 4) = v;   // R_0
  for (int c = 0; c < TCH - 1; ++c) {
    f32x4 q = *(const f32x4*)(Qb + ((long)bh * TCH + c) * 256 + t * 4);
    __syncthreads();
#pragma unroll
    for (int i = 0; i < 4; ++i) Ml[o * 17 + c4 * 4 + i] = q[i];
    __syncthreads();
    float nr[4] = {0.f, 0.f, 0.f, 0.f};
#pragma unroll
    for (int cc = 0; cc < 16; ++cc) {
      const float a = Al[o * 17 + cc];
#pragma unroll
      for (int i = 0; i < 4; ++i) nr[i] += a * Ml[cc * 17 + c4 * 4 + i];
    }
    __syncthreads();
#pragma unroll
    for (int i = 0; i < 4; ++i) Al[o * 17 + c4 * 4 + i] = nr[i];
    f32x4 w;
#pragma unroll
    for (int i = 0; i < 4; ++i) w[i] = nr[i];
    *(f32x4*)(Rb + ((long)bh * TCH + c + 1) * 256 + t * 4) = w;
  }
}

// ---------------------------------------------------------------------------
// Kernel 4: apply prefixes + fused mru_out/residual + new_state
// ---------------------------------------------------------------------------
__global__ __launch_bounds__(64) void scan_apply(const float* __restrict__ Ms,
                                                 const float* __restrict__ Rb,
                                                 const float* __restrict__ acts,
                                                 const float* __restrict__ wdown,
                                                 float* __restrict__ out) {
  const int task = blockIdx.x;
  const int bh = task >> 6, ch = task & 63;
  const int b = bh >> 3, h = bh & 7;
  const int t = threadIdx.x, o = t >> 2, c4 = t & 3;
  __shared__ float Al[272], Ml[272], Wd[272];
  f32x4 r0 = *(const f32x4*)(Rb + (long)task * 256 + t * 4);
#pragma unroll
  for (int i = 0; i < 4; ++i) Al[o * 17 + c4 * 4 + i] = r0[i];
  f32x4 wv = *(const f32x4*)(wdown + t * 4);   // wdown[c'][p], flat
#pragma unroll
  for (int i = 0; i < 4; ++i) Wd[o * 17 + c4 * 4 + i] = wv[i];
  for (int j = 0; j < WCH; ++j) {
    const int s = ch * WCH + j;
    f32x4 mv = *(const f32x4*)(Ms + ((long)bh * SS + s) * 256 + t * 4);
    __syncthreads();
#pragma unroll
    for (int i = 0; i < 4; ++i) Ml[o * 17 + c4 * 4 + i] = mv[i];
    __syncthreads();
    float nr[4] = {0.f, 0.f, 0.f, 0.f};
#pragma unroll
    for (int cc = 0; cc < 16; ++cc) {
      const float a = Al[o * 17 + cc];
#pragma unroll
      for (int i = 0; i < 4; ++i) nr[i] += a * Ml[cc * 17 + c4 * 4 + i];
    }
    __syncthreads();
#pragma unroll
    for (int i = 0; i < 4; ++i) Al[o * 17 + c4 * 4 + i] = nr[i];
    __syncthreads();
    float o2[4] = {0.f, 0.f, 0.f, 0.f};
#pragma unroll
    for (int p = 0; p < 16; ++p) {
      const float pr = Al[o * 17 + p];
#pragma unroll
      for (int i = 0; i < 4; ++i) o2[i] += pr * Wd[(c4 * 4 + i) * 17 + p];
    }
    const long e = ((long)(b * SS + s)) * EE + h * 256 + t * 4;
    f32x4 av = *(const f32x4*)(acts + e);
    f32x4 res;
#pragma unroll
    for (int i = 0; i < 4; ++i) res[i] = av[i] + o2[i];
    *(f32x4*)(out + e) = res;
    if (b == BB - 1) {
      f32x4 st;
#pragma unroll
      for (int i = 0; i < 4; ++i) st[i] = nr[i];
      *(f32x4*)(out + (long)BB * SS * EE + ((long)s * HH + h) * 256 + t * 4) = st;
    }
  }
}

// ---------------------------------------------------------------------------
// Kernel 5: LN2 + bf16 cast
// ---------------------------------------------------------------------------
__global__ __launch_bounds__(256) void ln2_cast(const float* __restrict__ act1,
                                                const float* __restrict__ lnw,
                                                unsigned short* __restrict__ xbf) {
  const int row = blockIdx.x;
  __shared__ float redA[4], redB[4];
  const int t = threadIdx.x, lane = t & 63, w = t >> 6;
  const float* xp = act1 + (long)row * EE;
  f32x4 v0 = *(const f32x4*)(xp + t * 4);
  f32x4 v1 = *(const f32x4*)(xp + 1024 + t * 4);
  float sum = 0.f, ss = 0.f;
#pragma unroll
  for (int i = 0; i < 4; ++i) {
    sum += v0[i] + v1[i];
    ss += v0[i] * v0[i] + v1[i] * v1[i];
  }
#pragma unroll
  for (int off = 32; off > 0; off >>= 1) {
    sum += __shfl_down(sum, off, 64);
    ss += __shfl_down(ss, off, 64);
  }
  if (lane == 0) { redA[w] = sum; redB[w] = ss; }
  __syncthreads();
  const float stot = redA[0] + redA[1] + redA[2] + redA[3];
  const float sstot = redB[0] + redB[1] + redB[2] + redB[3];
  const float mu = stot * (1.f / 2048.f);
  const float var = sstot * (1.f / 2048.f) - mu * mu;
  const float rs = rsqrtf(var + 1e-5f);
  f32x4 g0 = *(const f32x4*)(lnw + t * 4);
  f32x4 g1 = *(const f32x4*)(lnw + 1024 + t * 4);
  u16x4 o0, o1;
#pragma unroll
  for (int i = 0; i < 4; ++i) {
    o0[i] = f2bf((v0[i] - mu) * rs * g0[i]);
    o1[i] = f2bf((v1[i] - mu) * rs * g1[i]);
  }
  *(u16x4*)(xbf + (long)row * EE + t * 4) = o0;
  *(u16x4*)(xbf + (long)row * EE + 1024 + t * 4) = o1;
}

// ---------------------------------------------------------------------------
// GEMM 256x256, BK=64, 8 waves. R5/R9 8-phase derived-waits K-loop — the best
// measured configuration this session (656 us/GEMM = ~840 TF, total 1402 us).
// Session ceiling evidence: 7 choreography variants (128^2-2bar, 256^2-4ph,
// 8ph-burst, 8ph-derived, asm-reads, NoAlias-split, 128^2-multiblock,
// depth-3 vmcnt6) all land at 750-855 TF with MfmaUtil pinned 35-37% — the
// documented plain-HIP m97-family ceiling (36% of 2.5 PF dense). Breaking it
// requires the exact m201 interleave (3 faithful re-derivations nulled).
// EPI=0: gelu->bf16; EPI=1: f32 +=.
// ---------------------------------------------------------------------------
#define MFMA16 __builtin_amdgcn_mfma_f32_16x16x32_bf16
#define SBAR() __builtin_amdgcn_s_barrier()
#define SPRIO(x) __builtin_amdgcn_s_setprio(x)

template <int EPI>
__global__ __launch_bounds__(512, 2) void gemm8p(const short* __restrict__ A,
                                                 const short* __restrict__ Bt,
                                                 void* __restrict__ C,
                                                 int M, int N, int K) {
  __shared__ short lds[65536];  // 128 KiB = 8 x 16KB half-units
  const int tid = threadIdx.x;
  const int lane = tid & 63;
  const int wid = tid >> 6;
  const int wm = wid >> 2, wn = wid & 3;
  const int r = lane & 15, kq = lane >> 4;

  // bijective XCD swizzle (nwg % 8 == 0 for both GEMMs)
  const int nx = gridDim.x;
  const int orig = blockIdx.y * nx + blockIdx.x;
  const int nwg = nx * gridDim.y;
  const int swz = (orig & 7) * (nwg >> 3) + (orig >> 3);
  const int by = swz / nx, bx = swz - by * nx;
  const long m0 = (long)by * 256, n0 = (long)bx * 256;

  const int NT = K >> 6;   // K-tiles (NT even: K multiple of 128)

  f32x4 acc[8][4];
#pragma unroll
  for (int i = 0; i < 8; ++i)
#pragma unroll
    for (int j = 0; j < 4; ++j) acc[i][j] = (f32x4){0.f, 0.f, 0.f, 0.f};

  // stage addressing: one half-unit = 128 rows x 64 cols bf16 = 16KB = 2 loads/thread
  // rule-21: linear LDS dest, pre-swizzled global source (chunk ^ row&7)
  long sA0[2], sB0[2];
  int dst[2];
#pragma unroll
  for (int j = 0; j < 2; ++j) {
    const int c = tid + 512 * j;
    const int row = c >> 3;             // 0..127 within half-unit
    const int kc = (c & 7) ^ (row & 7);
    sA0[j] = (m0 + row) * (long)K + kc * 8;
    sB0[j] = (n0 + row) * (long)K + kc * 8;
    dst[j] = c * 8;                     // shorts within unit
  }
  const long hK = 128 * (long)K;

#define STG_A(t2, h) { const int _u = (((t2) & 1) * 2 + (h)) * 8192; \
  const long _o = (long)((t2) << 6) + (h) * hK; \
  _Pragma("unroll") for (int _j = 0; _j < 2; ++_j) \
    gl_lds16(A + sA0[_j] + _o, &lds[_u + dst[_j]]); }
#define STG_B(t2, h) { const int _u = 32768 + (((t2) & 1) * 2 + (h)) * 8192; \
  const long _o = (long)((t2) << 6) + (h) * hK; \
  _Pragma("unroll") for (int _j = 0; _j < 2; ++_j) \
    gl_lds16(Bt + sB0[_j] + _o, &lds[_u + dst[_j]]); }

  // ds_read offsets (shorts); swizzle bit depends only on r&7
  int offA[4], offB[2];
#pragma unroll
  for (int i = 0; i < 4; ++i) offA[i] = (wm * 64 + i * 16 + r) * 64;
#pragma unroll
  for (int j = 0; j < 2; ++j) offB[j] = (wn * 32 + j * 16 + r) * 64;
  const int c0 = (kq ^ (r & 7)) * 8;
  const int c1 = ((4 + kq) ^ (r & 7)) * 8;

  s16x8 af[4][2], bf[2][2];

#define RD_A(h, pb) { _Pragma("unroll") for (int _i = 0; _i < 4; ++_i) { \
    const int _ba = ((pb) + (h)) * 8192 + offA[_i]; \
    af[_i][0] = *(const s16x8*)&lds[_ba + c0]; \
    af[_i][1] = *(const s16x8*)&lds[_ba + c1]; } }
#define RD_B(h, pb) { _Pragma("unroll") for (int _j = 0; _j < 2; ++_j) { \
    const int _bb = 32768 + ((pb) + (h)) * 8192 + offB[_j]; \
    bf[_j][0] = *(const s16x8*)&lds[_bb + c0]; \
    bf[_j][1] = *(const s16x8*)&lds[_bb + c1]; } }
#define MFMA_Q(I0, J0) { _Pragma("unroll") for (int _i = 0; _i < 4; ++_i) \
  _Pragma("unroll") for (int _j = 0; _j < 2; ++_j) { \
    acc[(I0) + _i][(J0) + _j] = MFMA16(af[_i][0], bf[_j][0], acc[(I0) + _i][(J0) + _j], 0, 0, 0); \
    acc[(I0) + _i][(J0) + _j] = MFMA16(af[_i][1], bf[_j][1], acc[(I0) + _i][(J0) + _j], 0, 0, 0); } }

  // prologue: tile0 complete + Ah0(1) + Bh1(1); wait tile0 landed (leave 2 units)
  STG_A(0, 0); STG_A(0, 1); STG_B(0, 0); STG_B(0, 1);
  STG_A(1, 0); STG_B(1, 1);
  asm volatile("s_waitcnt vmcnt(4)" ::: "memory");
  SBAR();

  for (int t = 0; t < NT; t += 2) {
    const bool s2 = (t + 2) < NT, s3 = (t + 3) < NT;
    // ===== tile t (even, par 0) =====
    // ph1
    RD_A(0, 0); RD_B(0, 0);
    STG_A(t + 1, 1);
    asm volatile("s_waitcnt lgkmcnt(8)" ::: "memory");
    SBAR();
    SPRIO(1); MFMA_Q(0, 0); SPRIO(0);
    SBAR();
    // ph2
    RD_B(1, 0);
    STG_B(t + 1, 0);
    SBAR();
    SPRIO(1); MFMA_Q(0, 2); SPRIO(0);
    SBAR();
    // ph3
    RD_A(1, 0);
    if (s2) STG_A(t + 2, 0);
    SBAR();
    SPRIO(1); MFMA_Q(4, 2); SPRIO(0);
    SBAR();
    // ph4 (counted wait; vmcnt(0) on last pair — ph5 reads Bh0(t+1) staged ph2)
    RD_B(0, 0);
    if (s2) STG_B(t + 2, 1);
    SBAR();
    SPRIO(1); MFMA_Q(4, 0); SPRIO(0);
    if (s2) { asm volatile("s_waitcnt vmcnt(4)" ::: "memory"); }
    else    { asm volatile("s_waitcnt vmcnt(0)" ::: "memory"); }
    SBAR();
    // ===== tile t+1 (odd, par 1) =====
    // ph5
    RD_A(0, 2); RD_B(0, 2);
    if (s2) STG_A(t + 2, 1);
    asm volatile("s_waitcnt lgkmcnt(8)" ::: "memory");
    SBAR();
    SPRIO(1); MFMA_Q(0, 0); SPRIO(0);
    SBAR();
    // ph6
    RD_B(1, 2);
    if (s2) STG_B(t + 2, 0);
    SBAR();
    SPRIO(1); MFMA_Q(0, 2); SPRIO(0);
    SBAR();
    // ph7
    RD_A(1, 2);
    if (s3) STG_A(t + 3, 0);
    SBAR();
    SPRIO(1); MFMA_Q(4, 2); SPRIO(0);
    SBAR();
    // ph8
    RD_B(0, 2);
    if (s3) STG_B(t + 3, 1);
    SBAR();
    SPRIO(1); MFMA_Q(4, 0); SPRIO(0);
    if (s3) { asm volatile("s_waitcnt vmcnt(4)" ::: "memory"); }
    SBAR();
  }
  // after last ph8 SBAR all LDS reads are drained -> lds reusable by epilogue

  // ---------------- LDS-staged coalesced epilogue ----------------
  // Per-wave private region, no cross-wave sync needed.
  // Frag (i,j,rr): in-wave row rs = (i>>2)*64 + (i&3)*16 + kq*4 + rr (0..127)
  //                strip s = j>>1, in-strip col cs = (j&1)*16 + r (0..31)
  // global row = m0 + wm*64 + (rs&63) + (rs>>6)*128
  // global col = n0 + s*128 + wn*32 + cs
  if (EPI == 0) {
    // bf16 out, gelu. Region: 8192 shorts/wave; strip s at +s*4096, [128][32].
    unsigned short* Wl = (unsigned short*)lds + wid * 8192;
#pragma unroll
    for (int i = 0; i < 8; ++i)
#pragma unroll
      for (int j = 0; j < 4; ++j)
#pragma unroll
        for (int rr = 0; rr < 4; ++rr) {
          const int rs = (i >> 2) * 64 + (i & 3) * 16 + kq * 4 + rr;
          const int cs = (j & 1) * 16 + r;
          const float v = acc[i][j][rr];
          const float g = 0.5f * v * (1.0f + erff(v * 0.70710678118654752f));
          Wl[(j >> 1) * 4096 + rs * 32 + cs] = f2bf(g);
        }
    unsigned short* Cb = (unsigned short*)C;
#pragma unroll
    for (int s = 0; s < 2; ++s) {
      const long cg = n0 + s * 128 + wn * 32 + (lane & 3) * 8;
#pragma unroll
      for (int it = 0; it < 8; ++it) {
        const int rs = it * 16 + (lane >> 2);
        u16x8 v = *(const u16x8*)&Wl[s * 4096 + rs * 32 + (lane & 3) * 8];
        const long rg = m0 + wm * 64 + (rs & 63) + (rs >> 6) * 128;
        *(u16x8*)&Cb[rg * N + cg] = v;   // 16B coalesced store
      }
    }
  } else {
    // f32 +=. Region: 4096 floats/wave, one strip [128][32] at a time.
    float* Wl = (float*)lds + wid * 4096;
    float* Cf = (float*)C;
#pragma unroll
    for (int s = 0; s < 2; ++s) {
#pragma unroll
      for (int i = 0; i < 8; ++i)
#pragma unroll
        for (int j = 0; j < 2; ++j)
#pragma unroll
          for (int rr = 0; rr < 4; ++rr) {
            const int rs = (i >> 2) * 64 + (i & 3) * 16 + kq * 4 + rr;
            const int cs = j * 16 + r;
            Wl[rs * 32 + cs] = acc[i][s * 2 + j][rr];
          }
      const long cg = n0 + s * 128 + wn * 32 + (lane & 7) * 4;
#pragma unroll
      for (int it = 0; it < 16; ++it) {
        const int rs = it * 8 + (lane >> 3);
        f32x4 v = *(const f32x4*)&Wl[rs * 32 + (lane & 7) * 4];
        const long rg = m0 + wm * 64 + (rs & 63) + (rs >> 6) * 128;
        float* p = &Cf[rg * N + cg];
        f32x4 o = *(const f32x4*)p;     // 16B coalesced load
#pragma unroll
        for (int e = 0; e < 4; ++e) o[e] += v[e];
        *(f32x4*)p = o;                 // 16B coalesced store
      }
    }
  }
#undef STG_A
#undef STG_B
#undef RD_A
#undef RD_B
#undef MFMA_Q
}

// ---------------------------------------------------------------------------
extern "C" void kernel_launch(void* const* d_in, const int* in_sizes, int n_in,
                              void* d_out, int out_size, void* d_ws, size_t ws_size,
                              hipStream_t stream) {
  const float* acts = (const float*)d_in[0];   // (B,S,E)
  const float* last = (const float*)d_in[1];   // (B,H,O,O)
  const float* ln1w = (const float*)d_in[2];   // (E)
  const float* ln2w = (const float*)d_in[3];   // (E)
  const float* wup = (const float*)d_in[4];    // (O,C)
  const float* wdn = (const float*)d_in[5];    // (C,O)
  const float* w1 = (const float*)d_in[6];     // (4E,E)
  const float* w2 = (const float*)d_in[7];     // (E,4E)
  float* out = (float*)d_out;

  char* ws = (char*)d_ws;
  // ws layout: [xbf 64MB][w1b 32MB][w2b 32MB][X: Ms(128MB)+Q(4MB)+R(4MB) | h1(256MB)]
  unsigned short* xbf = (unsigned short*)ws;                     // 16384*2048 bf16
  unsigned short* w1b = (unsigned short*)(ws + 67108864);        // 8192*2048 bf16
  unsigned short* w2b = (unsigned short*)(ws + 67108864 + 33554432);
  char* X = ws + 134217728;
  float* Ms = (float*)X;                                         // [64][2048][256] f32
  float* Qb = (float*)(X + 134217728);
  float* Rb = (float*)(X + 134217728 + 4194304);
  unsigned short* h1 = (unsigned short*)X;                       // overlays Ms/Q/R

  cast2_bf16<<<16384, 256, 0, stream>>>(w1, w1b, w2, w2b, (long)8192 * 2048);
  ln1_newm<<<BB * SS, 256, 0, stream>>>(acts, ln1w, wup, Ms);
  chunk_prod<<<BB * HH * TCH, 64, 0, stream>>>(Ms, Qb);
  chunk_scan<<<BB * HH, 64, 0, stream>>>(last, Qb, Rb);
  scan_apply<<<BB * HH * TCH, 64, 0, stream>>>(Ms, Rb, acts, wdn, out);
  ln2_cast<<<BB * SS, 256, 0, stream>>>(out, ln2w, xbf);
  dim3 g1(8192 / 256, 16384 / 256);
  gemm8p<0><<<g1, 512, 0, stream>>>((const short*)xbf, (const short*)w1b,
                                    (void*)h1, 16384, 8192, 2048);
  dim3 g2(2048 / 256, 16384 / 256);
  gemm8p<1><<<g2, 512, 0, stream>>>((const short*)h1, (const short*)w2b,
                                    (void*)out, 16384, 2048, 8192);
}